// Round 9
// baseline (453.790 us; speedup 1.0000x reference)
//
#include <hip/hip_runtime.h>
#include <hip/hip_bf16.h>

#define N_NODES 20000
#define N_EDGES 320000
#define N_ADJ   4
#define D       256
#define DH      128              // packed bf16x2 dwords per feature row
#define RPA     20004            // row_ptr2 stride per adjacency (int4 elements)

// bucketed CSR build (block-private staging: NO global atomics)
#define NBUCK   79               // buckets of 256 rows (20000/256 -> 79)
#define NGRP    40               // staging groups = append blocks per adjacency
#define EPB     8000             // edges per append block (40 * 8000 = 320000)
#define GCAP    192              // cap per (adj,bucket,block) cell: mu=102, +9sd
#define BMAX    4736             // max records per bucket in LDS: mu=4096, +10sd
#define NCHUNK  4                // column chunks of 5000 (2.56 MB bf16 table slice)

typedef __attribute__((ext_vector_type(8))) short bf8;   // 8 bf16 (4 VGPRs)
typedef __attribute__((ext_vector_type(4))) float f4;    // MFMA accumulator

// ---------------------------------------------------------------------------
// bf16 pack/unpack helpers (RNE rounding; values are finite)
// ---------------------------------------------------------------------------

__device__ __forceinline__ unsigned f2bf_bits(float x) {
    unsigned u = __float_as_uint(x);
    return (u + 0x7FFFu + ((u >> 16) & 1u)) >> 16;
}
__device__ __forceinline__ unsigned pack_bf2(float lo, float hi) {
    return f2bf_bits(lo) | (f2bf_bits(hi) << 16);
}
__device__ __forceinline__ float bf_lo(unsigned p) { return __uint_as_float(p << 16); }
__device__ __forceinline__ float bf_hi(unsigned p) { return __uint_as_float(p & 0xFFFF0000u); }

// ---------------------------------------------------------------------------
// Pass A: append edges into BLOCK-PRIVATE (adj, bucket, block) staging cells.
// LDS atomics only.  Record: .x = (bf16(val)<<16)|col,
//                            .y = (row & 255) | (col_chunk << 8).
// ---------------------------------------------------------------------------

__global__ __launch_bounds__(1024) void append_kernel(const int* __restrict__ rows,
                                                      const int* __restrict__ cols,
                                                      const float* __restrict__ vals,
                                                      int* __restrict__ cnt,
                                                      uint2* __restrict__ stage) {
    __shared__ int lcnt[NBUCK];
    int g = blockIdx.x, a = blockIdx.y, t = threadIdx.x;
    if (t < NBUCK) lcnt[t] = 0;
    __syncthreads();
    int e0 = g * EPB;
    #pragma unroll 1
    for (int i = 0; i < EPB; i += 1024) {
        int e = e0 + i + t;
        if (i + t < EPB) {
            int r   = rows[a * N_EDGES + e];
            int c   = cols[a * N_EDGES + e];
            float v = vals[a * N_EDGES + e];
            int b   = r >> 8;
            int ch  = c / 5000;                   // column chunk 0..3
            int idx = atomicAdd(&lcnt[b], 1);     // LDS atomic
            if (idx < GCAP) {
                stage[(size_t)((a * NBUCK + b) * NGRP + g) * GCAP + idx] =
                    make_uint2((f2bf_bits(v) << 16) | (unsigned)c,
                               (unsigned)((r & 255) | (ch << 8)));
            }
        }
    }
    __syncthreads();
    if (t < NBUCK) cnt[(a * NBUCK + t) * NGRP + g] = min(lcnt[t], GCAP);
}

// ---------------------------------------------------------------------------
// Exclusive scan of bucket totals -> global bucket bases (4 blocks x 128 thr).
// ---------------------------------------------------------------------------

__global__ __launch_bounds__(128) void bscan_kernel(const int* __restrict__ cnt,
                                                    int* __restrict__ bbase) {
    int a = blockIdx.x, t = threadIdx.x;
    __shared__ int buf[128];
    int tot = 0;
    if (t < NBUCK) {
        for (int g = 0; g < NGRP; ++g) tot += cnt[(a * NBUCK + t) * NGRP + g];
    }
    buf[t] = tot;
    __syncthreads();
    for (int off = 1; off < 128; off <<= 1) {
        int add = (t >= off) ? buf[t - off] : 0;
        __syncthreads();
        buf[t] += add;
        __syncthreads();
    }
    if (t < NBUCK) bbase[a * 80 + t] = buf[t] - tot;   // exclusive base
}

// ---------------------------------------------------------------------------
// Pass B: one block per (adj,bucket).  Counting sort by bin = lrow*4 + chunk
// (1024 bins; thread t owns row t's 4 bins).  Writes final 4 B CSR records
// plus row_ptr2: one int4 of chunk sub-segment starts per row (+ sentinel).
// ---------------------------------------------------------------------------

__global__ __launch_bounds__(256) void bsort_kernel(const int* __restrict__ cnt,
                                                    const int* __restrict__ bbase,
                                                    const uint2* __restrict__ stage,
                                                    unsigned* __restrict__ csr,
                                                    int4* __restrict__ row_ptr2) {
    __shared__ uint2 recs[BMAX];
    __shared__ int binb[1024];    // counts -> bin bases
    __shared__ int offs[1024];
    __shared__ int scn[256];
    int b = blockIdx.x, a = blockIdx.y, t = threadIdx.x;

    int goff = 0;
    #pragma unroll 1
    for (int g = 0; g < NGRP; ++g) {
        int c = cnt[(a * NBUCK + b) * NGRP + g];
        const uint2* src = stage + (size_t)((a * NBUCK + b) * NGRP + g) * GCAP;
        for (int i = t; i < c; i += 256) {
            int d = goff + i;
            if (d < BMAX) recs[d] = src[i];
        }
        goff += c;
    }
    int total = min(goff, BMAX);

    #pragma unroll
    for (int j = 0; j < 4; ++j) { binb[t * 4 + j] = 0; offs[t * 4 + j] = 0; }
    __syncthreads();
    for (int i = t; i < total; i += 256) {
        unsigned y = recs[i].y;
        atomicAdd(&binb[(y & 255u) * 4 + (y >> 8)], 1);
    }
    __syncthreads();
    int c0 = binb[t * 4], c1 = binb[t * 4 + 1], c2 = binb[t * 4 + 2], c3 = binb[t * 4 + 3];
    int ts = c0 + c1 + c2 + c3;
    scn[t] = ts;
    __syncthreads();
    for (int off = 1; off < 256; off <<= 1) {
        int add = (t >= off) ? scn[t - off] : 0;
        __syncthreads();
        scn[t] += add;
        __syncthreads();
    }
    int e0 = scn[t] - ts;             // exclusive prefix for bin 4t
    int e1 = e0 + c0, e2 = e1 + c1, e3 = e2 + c2;
    binb[t * 4] = e0; binb[t * 4 + 1] = e1; binb[t * 4 + 2] = e2; binb[t * 4 + 3] = e3;
    __syncthreads();

    int gbase = bbase[a * 80 + b];
    for (int i = t; i < total; i += 256) {
        unsigned y = recs[i].y;
        int bin = (y & 255u) * 4 + (y >> 8);
        int pos = binb[bin] + atomicAdd(&offs[bin], 1);
        csr[(size_t)a * N_EDGES + gbase + pos] = recs[i].x;
    }
    int r = b * 256 + t;
    if (r <= N_NODES)
        row_ptr2[(size_t)a * RPA + r] =
            make_int4(gbase + e0, gbase + e1, gbase + e2, gbase + e3);
}

// ---------------------------------------------------------------------------
// W -> fragment-ordered bf16 hi/lo tables (one uint4 per lane per (ks,n) tile).
// B frag layout (16x16x32): n_idx = lane&15, k = ks*32 + (lane>>4)*8 + j.
// ---------------------------------------------------------------------------

__global__ __launch_bounds__(256) void wfrag_kernel(const float* __restrict__ W,
                                                    uint4* __restrict__ wh,
                                                    uint4* __restrict__ wl) {
    int g = blockIdx.x * 256 + threadIdx.x;   // 0..8191 = (ks*16+n)*64 + lane
    int lane = g & 63;
    int tile = g >> 6;                        // ks*16 + n
    int ks = tile >> 4, n = tile & 15;
    int m = lane & 15, quad = lane >> 4;
    int col = n * 16 + m;
    int k0  = ks * 32 + quad * 8;
    unsigned hbits[8], lbits[8];
    #pragma unroll
    for (int j = 0; j < 8; ++j) {
        float v = W[(k0 + j) * D + col];
        unsigned hb = f2bf_bits(v);
        float lo = v - __uint_as_float(hb << 16);
        hbits[j] = hb;
        lbits[j] = f2bf_bits(lo);
    }
    uint4 hh, ll;
    hh.x = hbits[0] | (hbits[1] << 16); hh.y = hbits[2] | (hbits[3] << 16);
    hh.z = hbits[4] | (hbits[5] << 16); hh.w = hbits[6] | (hbits[7] << 16);
    ll.x = lbits[0] | (lbits[1] << 16); ll.y = lbits[2] | (lbits[3] << 16);
    ll.z = lbits[4] | (lbits[5] << 16); ll.w = lbits[6] | (lbits[7] << 16);
    wh[g] = hh;
    wl[g] = ll;
}

// ---------------------------------------------------------------------------
// h = x @ W + b via bf16 MFMA hi/lo compensation (f32-accurate).  Block =
// 4 waves = 4 row tiles; B frags staged via double-buffered LDS.
// ---------------------------------------------------------------------------

__global__ __launch_bounds__(256) void mfma_matmul_kernel(const float* __restrict__ x,
                                                          const uint4* __restrict__ wh,
                                                          const uint4* __restrict__ wl,
                                                          const float* __restrict__ b,
                                                          unsigned* __restrict__ hp) {
    __shared__ uint4 lbuf[2][1024];           // [buf][ks*128 + hl*64 + lane], 32 KB
    int t = threadIdx.x, wid = t >> 6, lane = t & 63;
    int r0 = (blockIdx.x * 4 + wid) * 16;
    bool active = r0 < N_NODES;
    int m = lane & 15, quad = lane >> 4;

    bf8 ah[8], al[8];
    if (active) {
        const float* xr = x + (size_t)(r0 + m) * D + quad * 8;
        #pragma unroll
        for (int ks = 0; ks < 8; ++ks) {
            float4 v0 = *(const float4*)(xr + ks * 32);
            float4 v1 = *(const float4*)(xr + ks * 32 + 4);
            float xs[8] = {v0.x, v0.y, v0.z, v0.w, v1.x, v1.y, v1.z, v1.w};
            #pragma unroll
            for (int j = 0; j < 8; ++j) {
                unsigned hb = f2bf_bits(xs[j]);
                float lo = xs[j] - __uint_as_float(hb << 16);
                ah[ks][j] = (short)hb;
                al[ks][j] = (short)f2bf_bits(lo);
            }
        }
    }

    // prologue: stage n=0 fragments
    #pragma unroll
    for (int j = 0; j < 4; ++j) {
        int idx = j * 256 + t;
        int ks = idx >> 7, hl = (idx >> 6) & 1, ln = idx & 63;
        lbuf[0][idx] = (hl ? wl : wh)[(ks * 16 + 0) * 64 + ln];
    }
    __syncthreads();

    for (int n = 0; n < 16; ++n) {
        int cur = n & 1, nxt = cur ^ 1;
        uint4 pre[4];
        if (n < 15) {
            #pragma unroll
            for (int j = 0; j < 4; ++j) {
                int idx = j * 256 + t;
                int ks = idx >> 7, hl = (idx >> 6) & 1, ln = idx & 63;
                pre[j] = (hl ? wl : wh)[(ks * 16 + (n + 1)) * 64 + ln];
            }
        }
        if (active) {
            f4 c = {0.f, 0.f, 0.f, 0.f};
            #pragma unroll
            for (int ks = 0; ks < 8; ++ks) {
                bf8 bh = *(bf8*)&lbuf[cur][ks * 128 + lane];
                bf8 bl = *(bf8*)&lbuf[cur][ks * 128 + 64 + lane];
                c = __builtin_amdgcn_mfma_f32_16x16x32_bf16(ah[ks], bh, c, 0, 0, 0);
                c = __builtin_amdgcn_mfma_f32_16x16x32_bf16(al[ks], bh, c, 0, 0, 0);
                c = __builtin_amdgcn_mfma_f32_16x16x32_bf16(ah[ks], bl, c, 0, 0, 0);
            }
            int col = n * 16 + m;
            float bb = b[col];
            #pragma unroll
            for (int reg = 0; reg < 4; ++reg) {
                float v = c[reg] + bb;            // (r0+quad*4+reg, col)
                float o = __shfl_xor(v, 1, 64);   // partner column col^1
                if ((m & 1) == 0) {
                    hp[(r0 + quad * 4 + reg) * DH + (col >> 1)] = pack_bf2(v, o);
                }
            }
        }
        if (n < 15) {
            __syncthreads();                      // all done reading lbuf[nxt]
            #pragma unroll
            for (int j = 0; j < 4; ++j) lbuf[nxt][j * 256 + t] = pre[j];
            __syncthreads();
        }
    }
}

// ---------------------------------------------------------------------------
// Gather one (row, adj, chunk) sub-segment.  ONE WAVE per row: lane owns
// features 4*lane..4*lane+3 (one uint2).  beg/end wave-uniform -> records in
// SGPRs.  n>=8: 8-deep pipeline; tail (<8): batch-load records then issue all
// feature loads before consuming (keeps MLP at short segment lengths).
// ---------------------------------------------------------------------------

__device__ __forceinline__ void gather_seg(const unsigned* __restrict__ E, int beg, int end,
                                           const uint2* __restrict__ feat2, int lane,
                                           float* __restrict__ s /* [4] */) {
    int n = end - beg;
    const unsigned* e = E + beg;
    int m8 = n & ~7;
    if (m8) {
        unsigned rec[8];
        #pragma unroll
        for (int j = 0; j < 8; ++j) rec[j] = e[j];
        for (int i = 8; ; i += 8) {
            uint2 p[8];
            #pragma unroll
            for (int j = 0; j < 8; ++j)
                p[j] = feat2[((rec[j] & 0xFFFFu) << 6) + lane];
            bool more = i < m8;
            unsigned nrec[8];
            if (more) {
                #pragma unroll
                for (int j = 0; j < 8; ++j) nrec[j] = e[i + j];
            }
            #pragma unroll
            for (int j = 0; j < 8; ++j) {
                float v = __uint_as_float(rec[j] & 0xFFFF0000u);
                s[0] += v * bf_lo(p[j].x);
                s[1] += v * bf_hi(p[j].x);
                s[2] += v * bf_lo(p[j].y);
                s[3] += v * bf_hi(p[j].y);
            }
            if (!more) break;
            #pragma unroll
            for (int j = 0; j < 8; ++j) rec[j] = nrec[j];
        }
    }
    int rem = n - m8;                 // 0..7, wave-uniform
    unsigned rec[7];
    uint2 p[7];
    #pragma unroll
    for (int j = 0; j < 7; ++j) if (j < rem) rec[j] = e[m8 + j];
    #pragma unroll
    for (int j = 0; j < 7; ++j) if (j < rem) p[j] = feat2[((rec[j] & 0xFFFFu) << 6) + lane];
    #pragma unroll
    for (int j = 0; j < 7; ++j) if (j < rem) {
        float v = __uint_as_float(rec[j] & 0xFFFF0000u);
        s[0] += v * bf_lo(p[j].x);
        s[1] += v * bf_hi(p[j].x);
        s[2] += v * bf_lo(p[j].y);
        s[3] += v * bf_hi(p[j].y);
    }
}

// ---------------------------------------------------------------------------
// Stage 1: input h (packed).  Chunk loop OUTERMOST (XCD L2 holds one 2.56 MB
// table slice at a time).  acc[4][4] in registers; bounds in SGPRs.
// ---------------------------------------------------------------------------

__global__ __launch_bounds__(256) void stage1_kernel(const uint2* __restrict__ hp2,
                                                     const int4* __restrict__ row_ptr2,
                                                     const unsigned* __restrict__ csr,
                                                     const float* __restrict__ wseq0,
                                                     const float* __restrict__ wres0,
                                                     const float* __restrict__ wres1,
                                                     uint2* __restrict__ s1p2,
                                                     uint2* __restrict__ s2p2,
                                                     float4* __restrict__ outp4) {
    int t = threadIdx.x, wid = t >> 6, lane = t & 63;
    int r = blockIdx.x * 4 + wid;
    int b0[N_ADJ], b1[N_ADJ], b2[N_ADJ], b3[N_ADJ], b4[N_ADJ];
    #pragma unroll
    for (int a = 0; a < N_ADJ; ++a) {
        const int4* rp = row_ptr2 + (size_t)a * RPA;
        int4 cu = rp[r];
        b0[a] = __builtin_amdgcn_readfirstlane(cu.x);
        b1[a] = __builtin_amdgcn_readfirstlane(cu.y);
        b2[a] = __builtin_amdgcn_readfirstlane(cu.z);
        b3[a] = __builtin_amdgcn_readfirstlane(cu.w);
        b4[a] = __builtin_amdgcn_readfirstlane(rp[r + 1].x);
    }
    float acc[N_ADJ][4];
    #pragma unroll
    for (int a = 0; a < N_ADJ; ++a)
        acc[a][0] = acc[a][1] = acc[a][2] = acc[a][3] = 0.f;
    #pragma unroll
    for (int c = 0; c < NCHUNK; ++c) {
        #pragma unroll
        for (int a = 0; a < N_ADJ; ++a) {
            int beg = (c == 0) ? b0[a] : (c == 1) ? b1[a] : (c == 2) ? b2[a] : b3[a];
            int end = (c == 0) ? b1[a] : (c == 1) ? b2[a] : (c == 2) ? b3[a] : b4[a];
            gather_seg(csr + (size_t)a * N_EDGES, beg, end, hp2, lane, acc[a]);
        }
    }
    const float third = 1.f / 3.f;
    float w0 = wseq0[0] * third, w1 = wseq0[1] * third, w2 = wseq0[2] * third;
    float q0 = wres0[0] * 0.25f, q1 = wres0[1] * 0.25f, q2 = wres0[2] * 0.25f, q3 = wres0[3] * 0.25f;
    float u0 = wres1[0] * third, u1 = wres1[1] * third, u2 = wres1[2] * third;
    float s1v[4], s2v[4], ov[4];
    #pragma unroll
    for (int j = 0; j < 4; ++j) {
        s1v[j] = w0 * acc[0][j] + w1 * acc[1][j] + w2 * acc[2][j];
        s2v[j] = q0 * acc[0][j] + q1 * acc[1][j] + q2 * acc[2][j] + q3 * acc[3][j];
        ov[j]  = u0 * acc[0][j] + u1 * acc[1][j] + u2 * acc[3][j];
    }
    int o = r * 64 + lane;
    s1p2[o]  = make_uint2(pack_bf2(s1v[0], s1v[1]), pack_bf2(s1v[2], s1v[3]));
    s2p2[o]  = make_uint2(pack_bf2(s2v[0], s2v[1]), pack_bf2(s2v[2], s2v[3]));
    outp4[o] = make_float4(ov[0], ov[1], ov[2], ov[3]);
}

// ---------------------------------------------------------------------------
// Stage 2: input s1 (packed).  s2 += seq-combo; out-partial += res-combo.
// ---------------------------------------------------------------------------

__global__ __launch_bounds__(256) void stage2_kernel(const uint2* __restrict__ s1p2,
                                                     const int4* __restrict__ row_ptr2,
                                                     const unsigned* __restrict__ csr,
                                                     const float* __restrict__ wseq0,
                                                     const float* __restrict__ wres1,
                                                     uint2* __restrict__ s2p2,
                                                     float4* __restrict__ outp4) {
    int t = threadIdx.x, wid = t >> 6, lane = t & 63;
    int r = blockIdx.x * 4 + wid;
    int b0[N_ADJ], b1[N_ADJ], b2[N_ADJ], b3[N_ADJ], b4[N_ADJ];
    #pragma unroll
    for (int a = 0; a < N_ADJ; ++a) {
        const int4* rp = row_ptr2 + (size_t)a * RPA;
        int4 cu = rp[r];
        b0[a] = __builtin_amdgcn_readfirstlane(cu.x);
        b1[a] = __builtin_amdgcn_readfirstlane(cu.y);
        b2[a] = __builtin_amdgcn_readfirstlane(cu.z);
        b3[a] = __builtin_amdgcn_readfirstlane(cu.w);
        b4[a] = __builtin_amdgcn_readfirstlane(rp[r + 1].x);
    }
    float acc[N_ADJ][4];
    #pragma unroll
    for (int a = 0; a < N_ADJ; ++a)
        acc[a][0] = acc[a][1] = acc[a][2] = acc[a][3] = 0.f;
    #pragma unroll
    for (int c = 0; c < NCHUNK; ++c) {
        #pragma unroll
        for (int a = 0; a < N_ADJ; ++a) {
            int beg = (c == 0) ? b0[a] : (c == 1) ? b1[a] : (c == 2) ? b2[a] : b3[a];
            int end = (c == 0) ? b1[a] : (c == 1) ? b2[a] : (c == 2) ? b3[a] : b4[a];
            gather_seg(csr + (size_t)a * N_EDGES, beg, end, s1p2, lane, acc[a]);
        }
    }
    const float third = 1.f / 3.f;
    float w3 = wseq0[3] * third, w4 = wseq0[4] * third, w5 = wseq0[5] * third;
    float u3 = wres1[3] * third, u4 = wres1[4] * third, u5 = wres1[5] * third;
    int o = r * 64 + lane;
    uint2 sp = s2p2[o];
    float c0 = bf_lo(sp.x) + w3 * acc[0][0] + w4 * acc[1][0] + w5 * acc[2][0];
    float c1 = bf_hi(sp.x) + w3 * acc[0][1] + w4 * acc[1][1] + w5 * acc[2][1];
    float c2 = bf_lo(sp.y) + w3 * acc[0][2] + w4 * acc[1][2] + w5 * acc[2][2];
    float c3 = bf_hi(sp.y) + w3 * acc[0][3] + w4 * acc[1][3] + w5 * acc[2][3];
    s2p2[o] = make_uint2(pack_bf2(c0, c1), pack_bf2(c2, c3));
    float4 op = outp4[o];
    op.x += u3 * acc[0][0] + u4 * acc[1][0] + u5 * acc[3][0];
    op.y += u3 * acc[0][1] + u4 * acc[1][1] + u5 * acc[3][1];
    op.z += u3 * acc[0][2] + u4 * acc[1][2] + u5 * acc[3][2];
    op.w += u3 * acc[0][3] + u4 * acc[1][3] + u5 * acc[3][3];
    outp4[o] = op;
}

// ---------------------------------------------------------------------------
// Stage 3: input s2 (adjacencies 0,1), add out-partial, LayerNorm (pure wave
// shuffle reduction), exact GELU.
// ---------------------------------------------------------------------------

__global__ __launch_bounds__(256) void stage3_kernel(const uint2* __restrict__ s2p2,
                                                     const int4* __restrict__ row_ptr2,
                                                     const unsigned* __restrict__ csr,
                                                     const float* __restrict__ wseq1,
                                                     float4* __restrict__ outp4) {
    int t = threadIdx.x, wid = t >> 6, lane = t & 63;
    int r = blockIdx.x * 4 + wid;
    int b0[2], b1[2], b2[2], b3[2], b4[2];
    #pragma unroll
    for (int a = 0; a < 2; ++a) {
        const int4* rp = row_ptr2 + (size_t)a * RPA;
        int4 cu = rp[r];
        b0[a] = __builtin_amdgcn_readfirstlane(cu.x);
        b1[a] = __builtin_amdgcn_readfirstlane(cu.y);
        b2[a] = __builtin_amdgcn_readfirstlane(cu.z);
        b3[a] = __builtin_amdgcn_readfirstlane(cu.w);
        b4[a] = __builtin_amdgcn_readfirstlane(rp[r + 1].x);
    }
    float acc[2][4];
    #pragma unroll
    for (int a = 0; a < 2; ++a)
        acc[a][0] = acc[a][1] = acc[a][2] = acc[a][3] = 0.f;
    #pragma unroll
    for (int c = 0; c < NCHUNK; ++c) {
        #pragma unroll
        for (int a = 0; a < 2; ++a) {
            int beg = (c == 0) ? b0[a] : (c == 1) ? b1[a] : (c == 2) ? b2[a] : b3[a];
            int end = (c == 0) ? b1[a] : (c == 1) ? b2[a] : (c == 2) ? b3[a] : b4[a];
            gather_seg(csr + (size_t)a * N_EDGES, beg, end, s2p2, lane, acc[a]);
        }
    }
    float e0 = wseq1[0] * 0.5f, e1 = wseq1[1] * 0.5f;
    int o = r * 64 + lane;
    float4 op = outp4[o];
    float v0 = op.x + e0 * acc[0][0] + e1 * acc[1][0];
    float v1 = op.y + e0 * acc[0][1] + e1 * acc[1][1];
    float v2 = op.z + e0 * acc[0][2] + e1 * acc[1][2];
    float v3 = op.w + e0 * acc[0][3] + e1 * acc[1][3];

    float sv = v0 + v1 + v2 + v3;
    float sq = v0 * v0 + v1 * v1 + v2 * v2 + v3 * v3;
    #pragma unroll
    for (int off = 32; off > 0; off >>= 1) {
        sv += __shfl_xor(sv, off, 64);
        sq += __shfl_xor(sq, off, 64);
    }
    float mu   = sv * (1.f / 256.f);
    float var  = sq * (1.f / 256.f) - mu * mu;
    float rstd = rsqrtf(var + 1e-5f);
    float y0 = (v0 - mu) * rstd;
    float y1 = (v1 - mu) * rstd;
    float y2 = (v2 - mu) * rstd;
    float y3 = (v3 - mu) * rstd;
    const float is2 = 0.70710678118654752440f;
    outp4[o] = make_float4(0.5f * y0 * (1.f + erff(y0 * is2)),
                           0.5f * y1 * (1.f + erff(y1 * is2)),
                           0.5f * y2 * (1.f + erff(y2 * is2)),
                           0.5f * y3 * (1.f + erff(y3 * is2)));
}

// ---------------------------------------------------------------------------

extern "C" void kernel_launch(void* const* d_in, const int* in_sizes, int n_in,
                              void* d_out, int out_size, void* d_ws, size_t ws_size,
                              hipStream_t stream) {
    const float* x     = (const float*)d_in[0];
    const int*   rows  = (const int*)d_in[1];
    const int*   cols  = (const int*)d_in[2];
    const float* vals  = (const float*)d_in[3];
    const float* W     = (const float*)d_in[4];
    const float* b     = (const float*)d_in[5];
    const float* wseq0 = (const float*)d_in[6];  // (2,3)
    const float* wseq1 = (const float*)d_in[7];  // (2,)
    const float* wres0 = (const float*)d_in[8];  // (1,4)
    const float* wres1 = (const float*)d_in[9];  // (2,3)
    float4* outp4 = (float4*)d_out;

    char* p = (char*)d_ws;
    unsigned* hp   = (unsigned*)p; p += (size_t)N_NODES * DH * 4;     // 10.24 MB
    unsigned* s1p  = (unsigned*)p; p += (size_t)N_NODES * DH * 4;     // 10.24 MB
    unsigned* s2p  = (unsigned*)p; p += (size_t)N_NODES * DH * 4;     // 10.24 MB
    int4* row_ptr2 = (int4*)p;     p += (size_t)N_ADJ * RPA * 16;     // 1.28 MB
    int* cnt       = (int*)p;      p += (N_ADJ * NBUCK * NGRP * 4 + 127) / 128 * 128;
    int* bbase     = (int*)p;      p += N_ADJ * 80 * 4;               // 1.3 KB
    uint4* wh      = (uint4*)p;    p += 8192 * 16;                    // 128 KB
    uint4* wl      = (uint4*)p;    p += 8192 * 16;                    // 128 KB
    unsigned* csr  = (unsigned*)p;                                    // 5.12 MB
    // staging overlays s1p/s2p (dead until stage1): 4*79*40*192*8 B = 19.4 MB
    uint2* stage   = (uint2*)s1p;

    append_kernel<<<dim3(NGRP, N_ADJ), 1024, 0, stream>>>(rows, cols, vals, cnt, stage);
    bscan_kernel<<<N_ADJ, 128, 0, stream>>>(cnt, bbase);
    bsort_kernel<<<dim3(NBUCK, N_ADJ), 256, 0, stream>>>(cnt, bbase, stage, csr, row_ptr2);

    wfrag_kernel<<<32, 256, 0, stream>>>(W, wh, wl);
    mfma_matmul_kernel<<<313, 256, 0, stream>>>(x, wh, wl, b, hp);

    stage1_kernel<<<N_NODES / 4, 256, 0, stream>>>((const uint2*)hp, row_ptr2, csr,
                                                   wseq0, wres0, wres1,
                                                   (uint2*)s1p, (uint2*)s2p, outp4);
    stage2_kernel<<<N_NODES / 4, 256, 0, stream>>>((const uint2*)s1p, row_ptr2, csr,
                                                   wseq0, wres1, (uint2*)s2p, outp4);
    stage3_kernel<<<N_NODES / 4, 256, 0, stream>>>((const uint2*)s2p, row_ptr2, csr,
                                                   wseq1, outp4);
}

// Round 10
// 330.689 us; speedup vs baseline: 1.3723x; 1.3723x over previous
//
#include <hip/hip_runtime.h>
#include <hip/hip_bf16.h>

#define N_NODES 20000
#define N_EDGES 320000
#define N_ADJ   4
#define D       256
#define DH      128              // packed bf16x2 dwords per feature row
#define RPA     20004            // row_ptr stride per adjacency (20001 rounded to x4)

// bucketed CSR build (block-private staging: NO global atomics)
#define NBUCK   79               // buckets of 256 rows (20000/256 -> 79)
#define NGRP    40               // staging groups = append blocks per adjacency
#define EPB     8000             // edges per append block (40 * 8000 = 320000)
#define GCAP    192              // cap per (adj,bucket,block) cell: mu=102, +9sd
#define BMAX    4736             // max records per bucket in LDS: mu=4096, +10sd

typedef __attribute__((ext_vector_type(8))) short bf8;   // 8 bf16 (4 VGPRs)
typedef __attribute__((ext_vector_type(4))) float f4;    // MFMA accumulator

// ---------------------------------------------------------------------------
// bf16 pack/unpack helpers (RNE rounding; values are finite)
// ---------------------------------------------------------------------------

__device__ __forceinline__ unsigned f2bf_bits(float x) {
    unsigned u = __float_as_uint(x);
    return (u + 0x7FFFu + ((u >> 16) & 1u)) >> 16;
}
__device__ __forceinline__ unsigned pack_bf2(float lo, float hi) {
    return f2bf_bits(lo) | (f2bf_bits(hi) << 16);
}
__device__ __forceinline__ float bf_lo(unsigned p) { return __uint_as_float(p << 16); }
__device__ __forceinline__ float bf_hi(unsigned p) { return __uint_as_float(p & 0xFFFF0000u); }

// ---------------------------------------------------------------------------
// Pass A: append edges into BLOCK-PRIVATE (adj, bucket, block) staging cells.
// Placement via LDS atomics only; per-cell counts stored directly (no global
// atomics anywhere).  Record: .x = (bf16(val)<<16)|col, .y = row & 255.
// ---------------------------------------------------------------------------

__global__ __launch_bounds__(1024) void append_kernel(const int* __restrict__ rows,
                                                      const int* __restrict__ cols,
                                                      const float* __restrict__ vals,
                                                      int* __restrict__ cnt,
                                                      uint2* __restrict__ stage) {
    __shared__ int lcnt[NBUCK];
    int g = blockIdx.x, a = blockIdx.y, t = threadIdx.x;
    if (t < NBUCK) lcnt[t] = 0;
    __syncthreads();
    int e0 = g * EPB;
    #pragma unroll 1
    for (int i = 0; i < EPB; i += 1024) {
        int e = e0 + i + t;
        if (i + t < EPB) {
            int r   = rows[a * N_EDGES + e];
            int c   = cols[a * N_EDGES + e];
            float v = vals[a * N_EDGES + e];
            int b   = r >> 8;
            int idx = atomicAdd(&lcnt[b], 1);     // LDS atomic
            if (idx < GCAP) {
                stage[(size_t)((a * NBUCK + b) * NGRP + g) * GCAP + idx] =
                    make_uint2((f2bf_bits(v) << 16) | (unsigned)c, (unsigned)(r & 255));
            }
        }
    }
    __syncthreads();
    if (t < NBUCK) cnt[(a * NBUCK + t) * NGRP + g] = min(lcnt[t], GCAP);
}

// ---------------------------------------------------------------------------
// Exclusive scan of bucket totals -> global bucket bases (4 blocks x 128 thr).
// ---------------------------------------------------------------------------

__global__ __launch_bounds__(128) void bscan_kernel(const int* __restrict__ cnt,
                                                    int* __restrict__ bbase) {
    int a = blockIdx.x, t = threadIdx.x;
    __shared__ int buf[128];
    int tot = 0;
    if (t < NBUCK) {
        for (int g = 0; g < NGRP; ++g) tot += cnt[(a * NBUCK + t) * NGRP + g];
    }
    buf[t] = tot;
    __syncthreads();
    for (int off = 1; off < 128; off <<= 1) {
        int add = (t >= off) ? buf[t - off] : 0;
        __syncthreads();
        buf[t] += add;
        __syncthreads();
    }
    if (t < NBUCK) bbase[a * 80 + t] = buf[t] - tot;   // exclusive base
}

// ---------------------------------------------------------------------------
// Pass B: one block per (adj,bucket).  Gather the 40 group segments to LDS,
// counting sort by local row (hist + block scan + LDS-atomic placement),
// write final 4 B CSR records (bucket-private window) + row_ptr entries.
// ---------------------------------------------------------------------------

__global__ __launch_bounds__(256) void bsort_kernel(const int* __restrict__ cnt,
                                                    const int* __restrict__ bbase,
                                                    const uint2* __restrict__ stage,
                                                    unsigned* __restrict__ csr,
                                                    int* __restrict__ row_ptr) {
    __shared__ uint2 recs[BMAX];
    __shared__ int scn[256];
    __shared__ int offs[256];
    int b = blockIdx.x, a = blockIdx.y, t = threadIdx.x;

    int goff = 0;
    #pragma unroll 1
    for (int g = 0; g < NGRP; ++g) {
        int c = cnt[(a * NBUCK + b) * NGRP + g];
        const uint2* src = stage + (size_t)((a * NBUCK + b) * NGRP + g) * GCAP;
        for (int i = t; i < c; i += 256) {
            int d = goff + i;
            if (d < BMAX) recs[d] = src[i];
        }
        goff += c;
    }
    int total = min(goff, BMAX);

    scn[t] = 0;
    offs[t] = 0;
    __syncthreads();
    for (int i = t; i < total; i += 256) atomicAdd(&scn[recs[i].y], 1);
    __syncthreads();
    int mycnt = scn[t];
    // inclusive block scan (Hillis-Steele) over 256 counts
    for (int off = 1; off < 256; off <<= 1) {
        int add = (t >= off) ? scn[t - off] : 0;
        __syncthreads();
        scn[t] += add;
        __syncthreads();
    }
    int excl = scn[t] - mycnt;        // exclusive prefix for local row t
    __syncthreads();
    scn[t] = excl;                    // publish exclusive bases
    __syncthreads();

    int gbase = bbase[a * 80 + b];
    for (int i = t; i < total; i += 256) {
        int lr  = recs[i].y;
        int pos = scn[lr] + atomicAdd(&offs[lr], 1);
        csr[(size_t)a * N_EDGES + gbase + pos] = recs[i].x;
    }
    int r = b * 256 + t;
    if (r <= N_NODES) row_ptr[(size_t)a * RPA + r] = gbase + excl;
}

// ---------------------------------------------------------------------------
// W -> fragment-ordered bf16 hi/lo tables (one uint4 per lane per (ks,n) tile).
// B frag layout (16x16x32): n_idx = lane&15, k = ks*32 + (lane>>4)*8 + j.
// ---------------------------------------------------------------------------

__global__ __launch_bounds__(256) void wfrag_kernel(const float* __restrict__ W,
                                                    uint4* __restrict__ wh,
                                                    uint4* __restrict__ wl) {
    int g = blockIdx.x * 256 + threadIdx.x;   // 0..8191 = (ks*16+n)*64 + lane
    int lane = g & 63;
    int tile = g >> 6;                        // ks*16 + n
    int ks = tile >> 4, n = tile & 15;
    int m = lane & 15, quad = lane >> 4;
    int col = n * 16 + m;
    int k0  = ks * 32 + quad * 8;
    unsigned hbits[8], lbits[8];
    #pragma unroll
    for (int j = 0; j < 8; ++j) {
        float v = W[(k0 + j) * D + col];
        unsigned hb = f2bf_bits(v);
        float lo = v - __uint_as_float(hb << 16);
        hbits[j] = hb;
        lbits[j] = f2bf_bits(lo);
    }
    uint4 hh, ll;
    hh.x = hbits[0] | (hbits[1] << 16); hh.y = hbits[2] | (hbits[3] << 16);
    hh.z = hbits[4] | (hbits[5] << 16); hh.w = hbits[6] | (hbits[7] << 16);
    ll.x = lbits[0] | (lbits[1] << 16); ll.y = lbits[2] | (lbits[3] << 16);
    ll.z = lbits[4] | (lbits[5] << 16); ll.w = lbits[6] | (lbits[7] << 16);
    wh[g] = hh;
    wl[g] = ll;
}

// ---------------------------------------------------------------------------
// h = x @ W + b via bf16 MFMA hi/lo compensation (f32-accurate).
// Grid 1250 = one block per 16-row tile; wave w computes col-tiles 4w..4w+3
// reading W-fragments straight from L2 (256 KB table, L2-resident).
// ~4.9 waves/SIMD occupancy (vs 1.2 in the 313-block version); no LDS.
// ---------------------------------------------------------------------------

__global__ __launch_bounds__(256) void mfma_matmul_kernel(const float* __restrict__ x,
                                                          const uint4* __restrict__ wh,
                                                          const uint4* __restrict__ wl,
                                                          const float* __restrict__ b,
                                                          unsigned* __restrict__ hp) {
    int t = threadIdx.x, wid = t >> 6, lane = t & 63;
    int r0 = blockIdx.x * 16;                 // 1250 * 16 = 20000 exactly
    int m = lane & 15, quad = lane >> 4;

    // Preload A fragments (hi/lo) for all 8 k-steps: x tile read once per wave.
    const float* xr = x + (size_t)(r0 + m) * D + quad * 8;
    bf8 ah[8], al[8];
    #pragma unroll
    for (int ks = 0; ks < 8; ++ks) {
        float4 v0 = *(const float4*)(xr + ks * 32);
        float4 v1 = *(const float4*)(xr + ks * 32 + 4);
        float xs[8] = {v0.x, v0.y, v0.z, v0.w, v1.x, v1.y, v1.z, v1.w};
        #pragma unroll
        for (int j = 0; j < 8; ++j) {
            unsigned hb = f2bf_bits(xs[j]);
            float lo = xs[j] - __uint_as_float(hb << 16);
            ah[ks][j] = (short)hb;
            al[ks][j] = (short)f2bf_bits(lo);
        }
    }

    #pragma unroll
    for (int i = 0; i < 4; ++i) {
        int n = wid * 4 + i;
        f4 c = {0.f, 0.f, 0.f, 0.f};
        #pragma unroll
        for (int ks = 0; ks < 8; ++ks) {
            uint4 bh4 = wh[(ks * 16 + n) * 64 + lane];
            uint4 bl4 = wl[(ks * 16 + n) * 64 + lane];
            bf8 bh = *(bf8*)&bh4;
            bf8 bl = *(bf8*)&bl4;
            c = __builtin_amdgcn_mfma_f32_16x16x32_bf16(ah[ks], bh, c, 0, 0, 0);
            c = __builtin_amdgcn_mfma_f32_16x16x32_bf16(al[ks], bh, c, 0, 0, 0);
            c = __builtin_amdgcn_mfma_f32_16x16x32_bf16(ah[ks], bl, c, 0, 0, 0);
        }
        int col = n * 16 + m;
        float bb = b[col];
        #pragma unroll
        for (int reg = 0; reg < 4; ++reg) {
            float v = c[reg] + bb;            // (r0+quad*4+reg, col)
            float o = __shfl_xor(v, 1, 64);   // partner column col^1
            if ((m & 1) == 0) {
                hp[(r0 + quad * 4 + reg) * DH + (col >> 1)] = pack_bf2(v, o);
            }
        }
    }
}

// ---------------------------------------------------------------------------
// Gather one (row, adj) segment.  ONE WAVE per row: lane owns features
// 4*lane..4*lane+3 (one uint2 = 2 packed dwords).  beg/end are wave-uniform
// (readfirstlane'd by caller) so edge records + val stay in SGPRs; the VALU
// path per edge is 1 dwordx2 load + 4 unpack + 4 FMA.  8-deep pipeline.
// ---------------------------------------------------------------------------

__device__ __forceinline__ void gather_seg(const unsigned* __restrict__ E, int beg, int end,
                                           const uint2* __restrict__ feat2, int lane,
                                           float* __restrict__ s /* [4] */) {
    int n = end - beg;
    const unsigned* e = E + beg;
    int m8 = n & ~7;
    if (m8) {
        unsigned rec[8];
        #pragma unroll
        for (int j = 0; j < 8; ++j) rec[j] = e[j];
        for (int i = 8; ; i += 8) {
            uint2 p[8];
            #pragma unroll
            for (int j = 0; j < 8; ++j)
                p[j] = feat2[((rec[j] & 0xFFFFu) << 6) + lane];
            bool more = i < m8;
            unsigned nrec[8];
            if (more) {
                #pragma unroll
                for (int j = 0; j < 8; ++j) nrec[j] = e[i + j];
            }
            #pragma unroll
            for (int j = 0; j < 8; ++j) {
                float v = __uint_as_float(rec[j] & 0xFFFF0000u);
                s[0] += v * bf_lo(p[j].x);
                s[1] += v * bf_hi(p[j].x);
                s[2] += v * bf_lo(p[j].y);
                s[3] += v * bf_hi(p[j].y);
            }
            if (!more) break;
            #pragma unroll
            for (int j = 0; j < 8; ++j) rec[j] = nrec[j];
        }
    }
    for (int i = m8; i < n; ++i) {
        unsigned rr = e[i];
        uint2 pp = feat2[((rr & 0xFFFFu) << 6) + lane];
        float vv = __uint_as_float(rr & 0xFFFF0000u);
        s[0] += vv * bf_lo(pp.x);
        s[1] += vv * bf_hi(pp.x);
        s[2] += vv * bf_lo(pp.y);
        s[3] += vv * bf_hi(pp.y);
    }
}

// ---------------------------------------------------------------------------
// Stage 1: input h (packed).  Emits s1, s2-partial (packed uint2), out-partial
// (f32 float4, into d_out).  4 waves per block = 4 rows.
// ---------------------------------------------------------------------------

__global__ __launch_bounds__(256) void stage1_kernel(const uint2* __restrict__ hp2,
                                                     const int* __restrict__ row_ptr,
                                                     const unsigned* __restrict__ csr,
                                                     const float* __restrict__ wseq0,
                                                     const float* __restrict__ wres0,
                                                     const float* __restrict__ wres1,
                                                     uint2* __restrict__ s1p2,
                                                     uint2* __restrict__ s2p2,
                                                     float4* __restrict__ outp4) {
    int t = threadIdx.x, wid = t >> 6, lane = t & 63;
    int r = blockIdx.x * 4 + wid;
    float acc[N_ADJ][4];
    #pragma unroll
    for (int a = 0; a < N_ADJ; ++a) {
        acc[a][0] = acc[a][1] = acc[a][2] = acc[a][3] = 0.f;
        const int* rp = row_ptr + (size_t)a * RPA;
        int beg = __builtin_amdgcn_readfirstlane(rp[r]);
        int end = __builtin_amdgcn_readfirstlane(rp[r + 1]);
        gather_seg(csr + (size_t)a * N_EDGES, beg, end, hp2, lane, acc[a]);
    }
    const float third = 1.f / 3.f;
    float w0 = wseq0[0] * third, w1 = wseq0[1] * third, w2 = wseq0[2] * third;
    float q0 = wres0[0] * 0.25f, q1 = wres0[1] * 0.25f, q2 = wres0[2] * 0.25f, q3 = wres0[3] * 0.25f;
    float u0 = wres1[0] * third, u1 = wres1[1] * third, u2 = wres1[2] * third;
    float s1v[4], s2v[4], ov[4];
    #pragma unroll
    for (int j = 0; j < 4; ++j) {
        s1v[j] = w0 * acc[0][j] + w1 * acc[1][j] + w2 * acc[2][j];
        s2v[j] = q0 * acc[0][j] + q1 * acc[1][j] + q2 * acc[2][j] + q3 * acc[3][j];
        ov[j]  = u0 * acc[0][j] + u1 * acc[1][j] + u2 * acc[3][j];
    }
    int o = r * 64 + lane;
    s1p2[o]  = make_uint2(pack_bf2(s1v[0], s1v[1]), pack_bf2(s1v[2], s1v[3]));
    s2p2[o]  = make_uint2(pack_bf2(s2v[0], s2v[1]), pack_bf2(s2v[2], s2v[3]));
    outp4[o] = make_float4(ov[0], ov[1], ov[2], ov[3]);
}

// ---------------------------------------------------------------------------
// Stage 2: input s1 (packed).  s2 += seq-combo; out-partial += res-combo.
// ---------------------------------------------------------------------------

__global__ __launch_bounds__(256) void stage2_kernel(const uint2* __restrict__ s1p2,
                                                     const int* __restrict__ row_ptr,
                                                     const unsigned* __restrict__ csr,
                                                     const float* __restrict__ wseq0,
                                                     const float* __restrict__ wres1,
                                                     uint2* __restrict__ s2p2,
                                                     float4* __restrict__ outp4) {
    int t = threadIdx.x, wid = t >> 6, lane = t & 63;
    int r = blockIdx.x * 4 + wid;
    float acc[N_ADJ][4];
    #pragma unroll
    for (int a = 0; a < N_ADJ; ++a) {
        acc[a][0] = acc[a][1] = acc[a][2] = acc[a][3] = 0.f;
        const int* rp = row_ptr + (size_t)a * RPA;
        int beg = __builtin_amdgcn_readfirstlane(rp[r]);
        int end = __builtin_amdgcn_readfirstlane(rp[r + 1]);
        gather_seg(csr + (size_t)a * N_EDGES, beg, end, s1p2, lane, acc[a]);
    }
    const float third = 1.f / 3.f;
    float w3 = wseq0[3] * third, w4 = wseq0[4] * third, w5 = wseq0[5] * third;
    float u3 = wres1[3] * third, u4 = wres1[4] * third, u5 = wres1[5] * third;
    int o = r * 64 + lane;
    uint2 sp = s2p2[o];
    float c0 = bf_lo(sp.x) + w3 * acc[0][0] + w4 * acc[1][0] + w5 * acc[2][0];
    float c1 = bf_hi(sp.x) + w3 * acc[0][1] + w4 * acc[1][1] + w5 * acc[2][1];
    float c2 = bf_lo(sp.y) + w3 * acc[0][2] + w4 * acc[1][2] + w5 * acc[2][2];
    float c3 = bf_hi(sp.y) + w3 * acc[0][3] + w4 * acc[1][3] + w5 * acc[2][3];
    s2p2[o] = make_uint2(pack_bf2(c0, c1), pack_bf2(c2, c3));
    float4 op = outp4[o];
    op.x += u3 * acc[0][0] + u4 * acc[1][0] + u5 * acc[3][0];
    op.y += u3 * acc[0][1] + u4 * acc[1][1] + u5 * acc[3][1];
    op.z += u3 * acc[0][2] + u4 * acc[1][2] + u5 * acc[3][2];
    op.w += u3 * acc[0][3] + u4 * acc[1][3] + u5 * acc[3][3];
    outp4[o] = op;
}

// ---------------------------------------------------------------------------
// Stage 3: input s2 (adjacencies 0,1), add out-partial, LayerNorm (pure wave
// shuffle reduction -- no LDS, no syncthreads), exact GELU.
// ---------------------------------------------------------------------------

__global__ __launch_bounds__(256) void stage3_kernel(const uint2* __restrict__ s2p2,
                                                     const int* __restrict__ row_ptr,
                                                     const unsigned* __restrict__ csr,
                                                     const float* __restrict__ wseq1,
                                                     float4* __restrict__ outp4) {
    int t = threadIdx.x, wid = t >> 6, lane = t & 63;
    int r = blockIdx.x * 4 + wid;
    float acc[2][4];
    #pragma unroll
    for (int a = 0; a < 2; ++a) {
        acc[a][0] = acc[a][1] = acc[a][2] = acc[a][3] = 0.f;
        const int* rp = row_ptr + (size_t)a * RPA;
        int beg = __builtin_amdgcn_readfirstlane(rp[r]);
        int end = __builtin_amdgcn_readfirstlane(rp[r + 1]);
        gather_seg(csr + (size_t)a * N_EDGES, beg, end, s2p2, lane, acc[a]);
    }
    float e0 = wseq1[0] * 0.5f, e1 = wseq1[1] * 0.5f;
    int o = r * 64 + lane;
    float4 op = outp4[o];
    float v0 = op.x + e0 * acc[0][0] + e1 * acc[1][0];
    float v1 = op.y + e0 * acc[0][1] + e1 * acc[1][1];
    float v2 = op.z + e0 * acc[0][2] + e1 * acc[1][2];
    float v3 = op.w + e0 * acc[0][3] + e1 * acc[1][3];

    float sv = v0 + v1 + v2 + v3;
    float sq = v0 * v0 + v1 * v1 + v2 * v2 + v3 * v3;
    #pragma unroll
    for (int off = 32; off > 0; off >>= 1) {
        sv += __shfl_xor(sv, off, 64);
        sq += __shfl_xor(sq, off, 64);
    }
    float mu   = sv * (1.f / 256.f);
    float var  = sq * (1.f / 256.f) - mu * mu;
    float rstd = rsqrtf(var + 1e-5f);
    float y0 = (v0 - mu) * rstd;
    float y1 = (v1 - mu) * rstd;
    float y2 = (v2 - mu) * rstd;
    float y3 = (v3 - mu) * rstd;
    const float is2 = 0.70710678118654752440f;
    outp4[o] = make_float4(0.5f * y0 * (1.f + erff(y0 * is2)),
                           0.5f * y1 * (1.f + erff(y1 * is2)),
                           0.5f * y2 * (1.f + erff(y2 * is2)),
                           0.5f * y3 * (1.f + erff(y3 * is2)));
}

// ---------------------------------------------------------------------------

extern "C" void kernel_launch(void* const* d_in, const int* in_sizes, int n_in,
                              void* d_out, int out_size, void* d_ws, size_t ws_size,
                              hipStream_t stream) {
    const float* x     = (const float*)d_in[0];
    const int*   rows  = (const int*)d_in[1];
    const int*   cols  = (const int*)d_in[2];
    const float* vals  = (const float*)d_in[3];
    const float* W     = (const float*)d_in[4];
    const float* b     = (const float*)d_in[5];
    const float* wseq0 = (const float*)d_in[6];  // (2,3)
    const float* wseq1 = (const float*)d_in[7];  // (2,)
    const float* wres0 = (const float*)d_in[8];  // (1,4)
    const float* wres1 = (const float*)d_in[9];  // (2,3)
    float4* outp4 = (float4*)d_out;

    char* p = (char*)d_ws;
    unsigned* hp  = (unsigned*)p; p += (size_t)N_NODES * DH * 4;      // 10.24 MB
    unsigned* s1p = (unsigned*)p; p += (size_t)N_NODES * DH * 4;      // 10.24 MB
    unsigned* s2p = (unsigned*)p; p += (size_t)N_NODES * DH * 4;      // 10.24 MB
    int* row_ptr  = (int*)p;      p += (size_t)N_ADJ * RPA * 4;       // 320 KB
    int* cnt      = (int*)p;      p += (N_ADJ * NBUCK * NGRP * 4 + 127) / 128 * 128; // ~50 KB
    int* bbase    = (int*)p;      p += N_ADJ * 80 * 4;                // 1.3 KB
    uint4* wh     = (uint4*)p;    p += 8192 * 16;                     // 128 KB
    uint4* wl     = (uint4*)p;    p += 8192 * 16;                     // 128 KB
    unsigned* csr = (unsigned*)p;                                     // 5.12 MB
    // staging overlays s1p/s2p (dead until stage1): 4*79*40*192*8 B = 19.4 MB
    uint2* stage  = (uint2*)s1p;

    append_kernel<<<dim3(NGRP, N_ADJ), 1024, 0, stream>>>(rows, cols, vals, cnt, stage);
    bscan_kernel<<<N_ADJ, 128, 0, stream>>>(cnt, bbase);
    bsort_kernel<<<dim3(NBUCK, N_ADJ), 256, 0, stream>>>(cnt, bbase, stage, csr, row_ptr);

    wfrag_kernel<<<32, 256, 0, stream>>>(W, wh, wl);
    mfma_matmul_kernel<<<1250, 256, 0, stream>>>(x, wh, wl, b, hp);

    stage1_kernel<<<N_NODES / 4, 256, 0, stream>>>((const uint2*)hp, row_ptr, csr,
                                                   wseq0, wres0, wres1,
                                                   (uint2*)s1p, (uint2*)s2p, outp4);
    stage2_kernel<<<N_NODES / 4, 256, 0, stream>>>((const uint2*)s1p, row_ptr, csr,
                                                   wseq0, wres1, (uint2*)s2p, outp4);
    stage3_kernel<<<N_NODES / 4, 256, 0, stream>>>((const uint2*)s2p, row_ptr, csr,
                                                   wseq1, outp4);
}

// Round 11
// 323.780 us; speedup vs baseline: 1.4015x; 1.0213x over previous
//
#include <hip/hip_runtime.h>
#include <hip/hip_bf16.h>

#define N_NODES 20000
#define N_EDGES 320000
#define N_ADJ   4
#define D       256
#define DH      128              // packed bf16x2 dwords per feature row
#define RPA     20004            // row_ptr stride per adjacency (20001 rounded to x4)

// bucketed CSR build (block-private staging: NO global atomics)
#define NBUCK   79               // buckets of 256 rows (20000/256 -> 79)
#define NGRP    40               // staging groups = append blocks per adjacency
#define EPB     8000             // edges per append block (40 * 8000 = 320000)
#define GCAP    192              // cap per (adj,bucket,block) cell: mu=102, +9sd
#define BMAX    4736             // max records per bucket in LDS: mu=4096, +10sd
#define MMBLK   1250             // matmul blocks inside buildmm_kernel

typedef __attribute__((ext_vector_type(8))) short bf8;   // 8 bf16 (4 VGPRs)
typedef __attribute__((ext_vector_type(4))) float f4;    // MFMA accumulator

// ---------------------------------------------------------------------------
// bf16 pack/unpack helpers (RNE rounding; values are finite)
// ---------------------------------------------------------------------------

__device__ __forceinline__ unsigned f2bf_bits(float x) {
    unsigned u = __float_as_uint(x);
    return (u + 0x7FFFu + ((u >> 16) & 1u)) >> 16;
}
__device__ __forceinline__ unsigned pack_bf2(float lo, float hi) {
    return f2bf_bits(lo) | (f2bf_bits(hi) << 16);
}
__device__ __forceinline__ float bf_lo(unsigned p) { return __uint_as_float(p << 16); }
__device__ __forceinline__ float bf_hi(unsigned p) { return __uint_as_float(p & 0xFFFF0000u); }

// ---------------------------------------------------------------------------
// prep_kernel: append (blocks g<40, all a) PARALLEL wfrag (g>=40, a==0).
// append: edges -> block-private (adj,bucket,block) staging cells via LDS
// atomics; per-cell counts stored directly (no global atomics anywhere).
// wfrag: W -> fragment-ordered bf16 hi/lo tables, grid-strided on 2 blocks.
// ---------------------------------------------------------------------------

__global__ __launch_bounds__(1024) void prep_kernel(const int* __restrict__ rows,
                                                    const int* __restrict__ cols,
                                                    const float* __restrict__ vals,
                                                    int* __restrict__ cnt,
                                                    uint2* __restrict__ stage,
                                                    const float* __restrict__ W,
                                                    uint4* __restrict__ wh,
                                                    uint4* __restrict__ wl) {
    __shared__ int lcnt[NBUCK];
    int g = blockIdx.x, a = blockIdx.y, t = threadIdx.x;

    if (g >= NGRP) {                          // ---- wfrag path (2 blocks, a==0)
        if (a != 0) return;
        for (int i = (g - NGRP) * 1024 + t; i < 8192; i += 2048) {
            int lane = i & 63;
            int tile = i >> 6;                // ks*16 + n
            int ks = tile >> 4, n = tile & 15;
            int m = lane & 15, quad = lane >> 4;
            int col = n * 16 + m;
            int k0  = ks * 32 + quad * 8;
            unsigned hbits[8], lbits[8];
            #pragma unroll
            for (int j = 0; j < 8; ++j) {
                float v = W[(k0 + j) * D + col];
                unsigned hb = f2bf_bits(v);
                float lo = v - __uint_as_float(hb << 16);
                hbits[j] = hb;
                lbits[j] = f2bf_bits(lo);
            }
            uint4 hh, ll;
            hh.x = hbits[0] | (hbits[1] << 16); hh.y = hbits[2] | (hbits[3] << 16);
            hh.z = hbits[4] | (hbits[5] << 16); hh.w = hbits[6] | (hbits[7] << 16);
            ll.x = lbits[0] | (lbits[1] << 16); ll.y = lbits[2] | (lbits[3] << 16);
            ll.z = lbits[4] | (lbits[5] << 16); ll.w = lbits[6] | (lbits[7] << 16);
            wh[i] = hh;
            wl[i] = ll;
        }
        return;
    }

    // ---- append path
    if (t < NBUCK) lcnt[t] = 0;
    __syncthreads();
    int e0 = g * EPB;
    #pragma unroll 1
    for (int i = 0; i < EPB; i += 1024) {
        int e = e0 + i + t;
        if (i + t < EPB) {
            int r   = rows[a * N_EDGES + e];
            int c   = cols[a * N_EDGES + e];
            float v = vals[a * N_EDGES + e];
            int b   = r >> 8;
            int idx = atomicAdd(&lcnt[b], 1);     // LDS atomic
            if (idx < GCAP) {
                stage[(size_t)((a * NBUCK + b) * NGRP + g) * GCAP + idx] =
                    make_uint2((f2bf_bits(v) << 16) | (unsigned)c, (unsigned)(r & 255));
            }
        }
    }
    __syncthreads();
    if (t < NBUCK) cnt[(a * NBUCK + t) * NGRP + g] = min(lcnt[t], GCAP);
}

// ---------------------------------------------------------------------------
// buildmm_kernel: matmul (blocks < MMBLK) PARALLEL bsort (blocks >= MMBLK).
//
// matmul: h = x @ W + b via bf16 MFMA hi/lo compensation (f32-accurate).
// One block per 16-row tile; wave w computes col-tiles 4w..4w+3 reading
// W-fragments straight from L2 (256 KB table, L2-resident).
//
// bsort: one block per (adj,bucket).  Computes its own global bucket base
// (parallel prefix sum over cnt -- replaces the old bscan kernel), gathers
// the 40 group segments to LDS, counting-sorts by local row, writes final
// 4 B CSR records + row_ptr entries.
// ---------------------------------------------------------------------------

__global__ __launch_bounds__(256) void buildmm_kernel(const float* __restrict__ x,
                                                      const uint4* __restrict__ wh,
                                                      const uint4* __restrict__ wl,
                                                      const float* __restrict__ bvec,
                                                      unsigned* __restrict__ hp,
                                                      const int* __restrict__ cnt,
                                                      const uint2* __restrict__ stage,
                                                      unsigned* __restrict__ csr,
                                                      int* __restrict__ row_ptr) {
    __shared__ uint2 recs[BMAX];
    __shared__ int scn[256];
    __shared__ int offs[256];
    __shared__ int gbase_s;
    int t = threadIdx.x;

    if (blockIdx.x < MMBLK) {                 // ---- matmul path
        int wid = t >> 6, lane = t & 63;
        int r0 = blockIdx.x * 16;             // 1250 * 16 = 20000 exactly
        int m = lane & 15, quad = lane >> 4;

        const float* xr = x + (size_t)(r0 + m) * D + quad * 8;
        bf8 ah[8], al[8];
        #pragma unroll
        for (int ks = 0; ks < 8; ++ks) {
            float4 v0 = *(const float4*)(xr + ks * 32);
            float4 v1 = *(const float4*)(xr + ks * 32 + 4);
            float xs[8] = {v0.x, v0.y, v0.z, v0.w, v1.x, v1.y, v1.z, v1.w};
            #pragma unroll
            for (int j = 0; j < 8; ++j) {
                unsigned hb = f2bf_bits(xs[j]);
                float lo = xs[j] - __uint_as_float(hb << 16);
                ah[ks][j] = (short)hb;
                al[ks][j] = (short)f2bf_bits(lo);
            }
        }

        #pragma unroll
        for (int i = 0; i < 4; ++i) {
            int n = wid * 4 + i;
            f4 c = {0.f, 0.f, 0.f, 0.f};
            #pragma unroll
            for (int ks = 0; ks < 8; ++ks) {
                uint4 bh4 = wh[(ks * 16 + n) * 64 + lane];
                uint4 bl4 = wl[(ks * 16 + n) * 64 + lane];
                bf8 bh = *(bf8*)&bh4;
                bf8 bl = *(bf8*)&bl4;
                c = __builtin_amdgcn_mfma_f32_16x16x32_bf16(ah[ks], bh, c, 0, 0, 0);
                c = __builtin_amdgcn_mfma_f32_16x16x32_bf16(al[ks], bh, c, 0, 0, 0);
                c = __builtin_amdgcn_mfma_f32_16x16x32_bf16(ah[ks], bl, c, 0, 0, 0);
            }
            int col = n * 16 + m;
            float bb = bvec[col];
            #pragma unroll
            for (int reg = 0; reg < 4; ++reg) {
                float v = c[reg] + bb;            // (r0+quad*4+reg, col)
                float o = __shfl_xor(v, 1, 64);   // partner column col^1
                if ((m & 1) == 0) {
                    hp[(r0 + quad * 4 + reg) * DH + (col >> 1)] = pack_bf2(v, o);
                }
            }
        }
        return;
    }

    // ---- bsort path
    int linear = blockIdx.x - MMBLK;          // 0..315
    int a = linear / NBUCK, b = linear % NBUCK;

    // global bucket base: sum of cnt[a][b'<b][*] (contiguous range of b*NGRP)
    if (t == 0) gbase_s = 0;
    __syncthreads();
    int part = 0;
    for (int i = t; i < b * NGRP; i += 256) part += cnt[a * (NBUCK * NGRP) + i];
    #pragma unroll
    for (int off = 32; off > 0; off >>= 1) part += __shfl_xor(part, off, 64);
    if ((t & 63) == 0) atomicAdd(&gbase_s, part);

    int goff = 0;
    #pragma unroll 1
    for (int g = 0; g < NGRP; ++g) {
        int c = cnt[(a * NBUCK + b) * NGRP + g];
        const uint2* src = stage + (size_t)((a * NBUCK + b) * NGRP + g) * GCAP;
        for (int i = t; i < c; i += 256) {
            int d = goff + i;
            if (d < BMAX) recs[d] = src[i];
        }
        goff += c;
    }
    int total = min(goff, BMAX);

    scn[t] = 0;
    offs[t] = 0;
    __syncthreads();
    for (int i = t; i < total; i += 256) atomicAdd(&scn[recs[i].y], 1);
    __syncthreads();
    int mycnt = scn[t];
    // inclusive block scan (Hillis-Steele) over 256 counts
    for (int off = 1; off < 256; off <<= 1) {
        int add = (t >= off) ? scn[t - off] : 0;
        __syncthreads();
        scn[t] += add;
        __syncthreads();
    }
    int excl = scn[t] - mycnt;        // exclusive prefix for local row t
    __syncthreads();
    scn[t] = excl;                    // publish exclusive bases
    __syncthreads();

    int gbase = gbase_s;
    for (int i = t; i < total; i += 256) {
        int lr  = recs[i].y;
        int pos = scn[lr] + atomicAdd(&offs[lr], 1);
        csr[(size_t)a * N_EDGES + gbase + pos] = recs[i].x;
    }
    int r = b * 256 + t;
    if (r <= N_NODES) row_ptr[(size_t)a * RPA + r] = gbase + excl;
}

// ---------------------------------------------------------------------------
// Gather one (row, adj) segment.  ONE WAVE per row: lane owns features
// 4*lane..4*lane+3 (one uint2 = 2 packed dwords).  beg/end are wave-uniform
// (readfirstlane'd by caller) so edge records + val stay in SGPRs; the VALU
// path per edge is 1 dwordx2 load + 4 unpack + 4 FMA.  8-deep pipeline.
// ---------------------------------------------------------------------------

__device__ __forceinline__ void gather_seg(const unsigned* __restrict__ E, int beg, int end,
                                           const uint2* __restrict__ feat2, int lane,
                                           float* __restrict__ s /* [4] */) {
    int n = end - beg;
    const unsigned* e = E + beg;
    int m8 = n & ~7;
    if (m8) {
        unsigned rec[8];
        #pragma unroll
        for (int j = 0; j < 8; ++j) rec[j] = e[j];
        for (int i = 8; ; i += 8) {
            uint2 p[8];
            #pragma unroll
            for (int j = 0; j < 8; ++j)
                p[j] = feat2[((rec[j] & 0xFFFFu) << 6) + lane];
            bool more = i < m8;
            unsigned nrec[8];
            if (more) {
                #pragma unroll
                for (int j = 0; j < 8; ++j) nrec[j] = e[i + j];
            }
            #pragma unroll
            for (int j = 0; j < 8; ++j) {
                float v = __uint_as_float(rec[j] & 0xFFFF0000u);
                s[0] += v * bf_lo(p[j].x);
                s[1] += v * bf_hi(p[j].x);
                s[2] += v * bf_lo(p[j].y);
                s[3] += v * bf_hi(p[j].y);
            }
            if (!more) break;
            #pragma unroll
            for (int j = 0; j < 8; ++j) rec[j] = nrec[j];
        }
    }
    for (int i = m8; i < n; ++i) {
        unsigned rr = e[i];
        uint2 pp = feat2[((rr & 0xFFFFu) << 6) + lane];
        float vv = __uint_as_float(rr & 0xFFFF0000u);
        s[0] += vv * bf_lo(pp.x);
        s[1] += vv * bf_hi(pp.x);
        s[2] += vv * bf_lo(pp.y);
        s[3] += vv * bf_hi(pp.y);
    }
}

// ---------------------------------------------------------------------------
// Stage 1: input h (packed).  Emits s1, s2-partial (packed uint2), out-partial
// (f32 float4, into d_out).  4 waves per block = 4 rows.
// ---------------------------------------------------------------------------

__global__ __launch_bounds__(256) void stage1_kernel(const uint2* __restrict__ hp2,
                                                     const int* __restrict__ row_ptr,
                                                     const unsigned* __restrict__ csr,
                                                     const float* __restrict__ wseq0,
                                                     const float* __restrict__ wres0,
                                                     const float* __restrict__ wres1,
                                                     uint2* __restrict__ s1p2,
                                                     uint2* __restrict__ s2p2,
                                                     float4* __restrict__ outp4) {
    int t = threadIdx.x, wid = t >> 6, lane = t & 63;
    int r = blockIdx.x * 4 + wid;
    float acc[N_ADJ][4];
    #pragma unroll
    for (int a = 0; a < N_ADJ; ++a) {
        acc[a][0] = acc[a][1] = acc[a][2] = acc[a][3] = 0.f;
        const int* rp = row_ptr + (size_t)a * RPA;
        int beg = __builtin_amdgcn_readfirstlane(rp[r]);
        int end = __builtin_amdgcn_readfirstlane(rp[r + 1]);
        gather_seg(csr + (size_t)a * N_EDGES, beg, end, hp2, lane, acc[a]);
    }
    const float third = 1.f / 3.f;
    float w0 = wseq0[0] * third, w1 = wseq0[1] * third, w2 = wseq0[2] * third;
    float q0 = wres0[0] * 0.25f, q1 = wres0[1] * 0.25f, q2 = wres0[2] * 0.25f, q3 = wres0[3] * 0.25f;
    float u0 = wres1[0] * third, u1 = wres1[1] * third, u2 = wres1[2] * third;
    float s1v[4], s2v[4], ov[4];
    #pragma unroll
    for (int j = 0; j < 4; ++j) {
        s1v[j] = w0 * acc[0][j] + w1 * acc[1][j] + w2 * acc[2][j];
        s2v[j] = q0 * acc[0][j] + q1 * acc[1][j] + q2 * acc[2][j] + q3 * acc[3][j];
        ov[j]  = u0 * acc[0][j] + u1 * acc[1][j] + u2 * acc[3][j];
    }
    int o = r * 64 + lane;
    s1p2[o]  = make_uint2(pack_bf2(s1v[0], s1v[1]), pack_bf2(s1v[2], s1v[3]));
    s2p2[o]  = make_uint2(pack_bf2(s2v[0], s2v[1]), pack_bf2(s2v[2], s2v[3]));
    outp4[o] = make_float4(ov[0], ov[1], ov[2], ov[3]);
}

// ---------------------------------------------------------------------------
// Stage 2: input s1 (packed).  s2 += seq-combo; out-partial += res-combo.
// ---------------------------------------------------------------------------

__global__ __launch_bounds__(256) void stage2_kernel(const uint2* __restrict__ s1p2,
                                                     const int* __restrict__ row_ptr,
                                                     const unsigned* __restrict__ csr,
                                                     const float* __restrict__ wseq0,
                                                     const float* __restrict__ wres1,
                                                     uint2* __restrict__ s2p2,
                                                     float4* __restrict__ outp4) {
    int t = threadIdx.x, wid = t >> 6, lane = t & 63;
    int r = blockIdx.x * 4 + wid;
    float acc[N_ADJ][4];
    #pragma unroll
    for (int a = 0; a < N_ADJ; ++a) {
        acc[a][0] = acc[a][1] = acc[a][2] = acc[a][3] = 0.f;
        const int* rp = row_ptr + (size_t)a * RPA;
        int beg = __builtin_amdgcn_readfirstlane(rp[r]);
        int end = __builtin_amdgcn_readfirstlane(rp[r + 1]);
        gather_seg(csr + (size_t)a * N_EDGES, beg, end, s1p2, lane, acc[a]);
    }
    const float third = 1.f / 3.f;
    float w3 = wseq0[3] * third, w4 = wseq0[4] * third, w5 = wseq0[5] * third;
    float u3 = wres1[3] * third, u4 = wres1[4] * third, u5 = wres1[5] * third;
    int o = r * 64 + lane;
    uint2 sp = s2p2[o];
    float c0 = bf_lo(sp.x) + w3 * acc[0][0] + w4 * acc[1][0] + w5 * acc[2][0];
    float c1 = bf_hi(sp.x) + w3 * acc[0][1] + w4 * acc[1][1] + w5 * acc[2][1];
    float c2 = bf_lo(sp.y) + w3 * acc[0][2] + w4 * acc[1][2] + w5 * acc[2][2];
    float c3 = bf_hi(sp.y) + w3 * acc[0][3] + w4 * acc[1][3] + w5 * acc[2][3];
    s2p2[o] = make_uint2(pack_bf2(c0, c1), pack_bf2(c2, c3));
    float4 op = outp4[o];
    op.x += u3 * acc[0][0] + u4 * acc[1][0] + u5 * acc[3][0];
    op.y += u3 * acc[0][1] + u4 * acc[1][1] + u5 * acc[3][1];
    op.z += u3 * acc[0][2] + u4 * acc[1][2] + u5 * acc[3][2];
    op.w += u3 * acc[0][3] + u4 * acc[1][3] + u5 * acc[3][3];
    outp4[o] = op;
}

// ---------------------------------------------------------------------------
// Stage 3: input s2 (adjacencies 0,1), add out-partial, LayerNorm (pure wave
// shuffle reduction -- no LDS, no syncthreads), exact GELU.
// ---------------------------------------------------------------------------

__global__ __launch_bounds__(256) void stage3_kernel(const uint2* __restrict__ s2p2,
                                                     const int* __restrict__ row_ptr,
                                                     const unsigned* __restrict__ csr,
                                                     const float* __restrict__ wseq1,
                                                     float4* __restrict__ outp4) {
    int t = threadIdx.x, wid = t >> 6, lane = t & 63;
    int r = blockIdx.x * 4 + wid;
    float acc[2][4];
    #pragma unroll
    for (int a = 0; a < 2; ++a) {
        acc[a][0] = acc[a][1] = acc[a][2] = acc[a][3] = 0.f;
        const int* rp = row_ptr + (size_t)a * RPA;
        int beg = __builtin_amdgcn_readfirstlane(rp[r]);
        int end = __builtin_amdgcn_readfirstlane(rp[r + 1]);
        gather_seg(csr + (size_t)a * N_EDGES, beg, end, s2p2, lane, acc[a]);
    }
    float e0 = wseq1[0] * 0.5f, e1 = wseq1[1] * 0.5f;
    int o = r * 64 + lane;
    float4 op = outp4[o];
    float v0 = op.x + e0 * acc[0][0] + e1 * acc[1][0];
    float v1 = op.y + e0 * acc[0][1] + e1 * acc[1][1];
    float v2 = op.z + e0 * acc[0][2] + e1 * acc[1][2];
    float v3 = op.w + e0 * acc[0][3] + e1 * acc[1][3];

    float sv = v0 + v1 + v2 + v3;
    float sq = v0 * v0 + v1 * v1 + v2 * v2 + v3 * v3;
    #pragma unroll
    for (int off = 32; off > 0; off >>= 1) {
        sv += __shfl_xor(sv, off, 64);
        sq += __shfl_xor(sq, off, 64);
    }
    float mu   = sv * (1.f / 256.f);
    float var  = sq * (1.f / 256.f) - mu * mu;
    float rstd = rsqrtf(var + 1e-5f);
    float y0 = (v0 - mu) * rstd;
    float y1 = (v1 - mu) * rstd;
    float y2 = (v2 - mu) * rstd;
    float y3 = (v3 - mu) * rstd;
    const float is2 = 0.70710678118654752440f;
    outp4[o] = make_float4(0.5f * y0 * (1.f + erff(y0 * is2)),
                           0.5f * y1 * (1.f + erff(y1 * is2)),
                           0.5f * y2 * (1.f + erff(y2 * is2)),
                           0.5f * y3 * (1.f + erff(y3 * is2)));
}

// ---------------------------------------------------------------------------

extern "C" void kernel_launch(void* const* d_in, const int* in_sizes, int n_in,
                              void* d_out, int out_size, void* d_ws, size_t ws_size,
                              hipStream_t stream) {
    const float* x     = (const float*)d_in[0];
    const int*   rows  = (const int*)d_in[1];
    const int*   cols  = (const int*)d_in[2];
    const float* vals  = (const float*)d_in[3];
    const float* W     = (const float*)d_in[4];
    const float* b     = (const float*)d_in[5];
    const float* wseq0 = (const float*)d_in[6];  // (2,3)
    const float* wseq1 = (const float*)d_in[7];  // (2,)
    const float* wres0 = (const float*)d_in[8];  // (1,4)
    const float* wres1 = (const float*)d_in[9];  // (2,3)
    float4* outp4 = (float4*)d_out;

    char* p = (char*)d_ws;
    unsigned* hp  = (unsigned*)p; p += (size_t)N_NODES * DH * 4;      // 10.24 MB
    unsigned* s1p = (unsigned*)p; p += (size_t)N_NODES * DH * 4;      // 10.24 MB
    unsigned* s2p = (unsigned*)p; p += (size_t)N_NODES * DH * 4;      // 10.24 MB
    int* row_ptr  = (int*)p;      p += (size_t)N_ADJ * RPA * 4;       // 320 KB
    int* cnt      = (int*)p;      p += (N_ADJ * NBUCK * NGRP * 4 + 127) / 128 * 128; // ~50 KB
    uint4* wh     = (uint4*)p;    p += 8192 * 16;                     // 128 KB
    uint4* wl     = (uint4*)p;    p += 8192 * 16;                     // 128 KB
    unsigned* csr = (unsigned*)p;                                     // 5.12 MB
    // staging overlays s1p/s2p (dead until stage1): 4*79*40*192*8 B = 19.4 MB
    uint2* stage  = (uint2*)s1p;

    // prep: append (40 blocks/adj) + wfrag (2 extra blocks on adj row 0)
    prep_kernel<<<dim3(NGRP + 2, N_ADJ), 1024, 0, stream>>>(rows, cols, vals, cnt,
                                                            stage, W, wh, wl);
    // buildmm: matmul (1250 blocks) + bsort w/ in-kernel base scan (316 blocks)
    buildmm_kernel<<<MMBLK + NBUCK * N_ADJ, 256, 0, stream>>>(x, wh, wl, b, hp,
                                                              cnt, stage, csr, row_ptr);

    stage1_kernel<<<N_NODES / 4, 256, 0, stream>>>((const uint2*)hp, row_ptr, csr,
                                                   wseq0, wres0, wres1,
                                                   (uint2*)s1p, (uint2*)s2p, outp4);
    stage2_kernel<<<N_NODES / 4, 256, 0, stream>>>((const uint2*)s1p, row_ptr, csr,
                                                   wseq0, wres1, (uint2*)s2p, outp4);
    stage3_kernel<<<N_NODES / 4, 256, 0, stream>>>((const uint2*)s2p, row_ptr, csr,
                                                   wseq1, outp4);
}